// Round 7
// baseline (81.587 us; speedup 1.0000x reference)
//
#include <hip/hip_runtime.h>
#include <hip/hip_bf16.h>

// Single-head causal attention, B=4096, T=64, C=128, H=64.
// One block (4 waves) per batch. Wave w owns query rows [16w,16w+16).
// All matmuls bf16 MFMA 16x16x32, operand-swapped; softmax lane-local.
// R6 post-mortem: compiler targets max occupancy -> VGPR=40 -> all loads
// serialized -> 100us latency-bound. R7: amdgpu_waves_per_eu(3,3) lowers the
// scheduler's occupancy target so the 12-wide W-load batches stay in flight.

typedef __bf16 bf16_t;
typedef __bf16 bf16x8 __attribute__((ext_vector_type(8)));
typedef __bf16 bf16x4 __attribute__((ext_vector_type(4)));
typedef float  f32x4  __attribute__((ext_vector_type(4)));

#define K_OFF   0        // K [s][h]  64x64 bf16, rowstride 128 B, swizzled
#define VT_OFF  8192     // VT [h][s] 64x64 bf16
#define QS_OFF  16384    // per-wave scratch (q then P): w*2048, 16x64 bf16
#define LDS_BYTES 24576

__device__ __forceinline__ int swz(int off, int row) { return off ^ ((row & 7) << 4); }

__device__ __forceinline__ bf16x8 pack8(float4 a, float4 b) {
    bf16x8 r;
    r[0] = (bf16_t)a.x; r[1] = (bf16_t)a.y; r[2] = (bf16_t)a.z; r[3] = (bf16_t)a.w;
    r[4] = (bf16_t)b.x; r[5] = (bf16_t)b.y; r[6] = (bf16_t)b.z; r[7] = (bf16_t)b.w;
    return r;
}

// W bf16 in ws: w2[(ks*192 + h)*32 + c]  (ks-major; per-ks slice = 12 KB)
__global__ void wcvt_kernel(const float* __restrict__ Wq, const float* __restrict__ Wk,
                            const float* __restrict__ Wv, bf16_t* __restrict__ w2)
{
    int i   = blockIdx.x * 256 + threadIdx.x;   // 6144 threads, 4 elems each
    int ks  = i / 1536;
    int rem = i - ks * 1536;
    int h   = rem >> 3;
    int c4  = (rem & 7) * 4;
    const float* wr = (h < 64) ? Wq + h * 128 : (h < 128) ? Wk + (h - 64) * 128
                                                          : Wv + (h - 128) * 128;
    float4 v = *reinterpret_cast<const float4*>(wr + ks * 32 + c4);
    bf16x4 pk;
    pk[0] = (bf16_t)v.x; pk[1] = (bf16_t)v.y; pk[2] = (bf16_t)v.z; pk[3] = (bf16_t)v.w;
    *reinterpret_cast<bf16x4*>(w2 + (ks * 192 + h) * 32 + c4) = pk;
}

template<bool USE_WS>
__global__ __launch_bounds__(256)
__attribute__((amdgpu_waves_per_eu(3, 3)))
void head_attn_kernel(const float* __restrict__ x,
                      const float* __restrict__ Wq,
                      const float* __restrict__ Wk,
                      const float* __restrict__ Wv,
                      const bf16_t* __restrict__ w2,
                      float* __restrict__ out)
{
    __shared__ __align__(16) char smem[LDS_BYTES];
    const int b    = blockIdx.x;
    const int tid  = threadIdx.x;
    const int w    = tid >> 6;
    const int lane = tid & 63;
    const int l15  = lane & 15;
    const int lg   = lane >> 4;
    const int t    = w * 16 + l15;          // lane's owned query/time row
    char* qscr = smem + QS_OFF + w * 2048;

    // ---- 8 independent x float4 loads, issued up front ----
    const float* xrow = x + (size_t)b * 8192 + t * 128 + lg * 8;
    float4 xr0 = *(const float4*)(xrow +   0), xr1 = *(const float4*)(xrow +   4);
    float4 xr2 = *(const float4*)(xrow +  32), xr3 = *(const float4*)(xrow +  36);
    float4 xr4 = *(const float4*)(xrow +  64), xr5 = *(const float4*)(xrow +  68);
    float4 xr6 = *(const float4*)(xrow +  96), xr7 = *(const float4*)(xrow + 100);

    bf16x8 xb[4];
    xb[0] = pack8(xr0, xr1); xb[1] = pack8(xr2, xr3);
    xb[2] = pack8(xr4, xr5); xb[3] = pack8(xr6, xr7);

    // ------------- QKV (swapped): D[h][t] = W[h][:] . x[t][:] --------------
    // acc[j]: h-tile j (q: 0..3, k: 4..7, v: 8..11); lane = col t, regs = 4 h rows
    f32x4 acc[12];
    #pragma unroll
    for (int j = 0; j < 12; ++j) acc[j] = (f32x4){0.f, 0.f, 0.f, 0.f};

    if constexpr (USE_WS) {
        const bf16_t* wbase = w2 + l15 * 32 + lg * 8;
        #pragma unroll
        for (int ks = 0; ks < 4; ++ks) {
            bf16x8 wf[12];                       // 12 x 16B loads batched in flight
            #pragma unroll
            for (int j = 0; j < 12; ++j)
                wf[j] = *reinterpret_cast<const bf16x8*>(wbase + ks * 6144 + j * 512);
            #pragma unroll
            for (int j = 0; j < 12; ++j)
                acc[j] = __builtin_amdgcn_mfma_f32_16x16x32_bf16(wf[j], xb[ks], acc[j], 0, 0, 0);
        }
    } else {
        const float* pw0 = Wq + l15 * 128;
        const float* pw1 = Wk + l15 * 128;
        const float* pw2 = Wv + l15 * 128;
        #pragma unroll
        for (int ks = 0; ks < 4; ++ks) {
            #pragma unroll
            for (int g = 0; g < 3; ++g) {        // groups of 4 j's: 8 loads in flight
                float4 wa[4], wc[4];
                #pragma unroll
                for (int jj = 0; jj < 4; ++jj) {
                    int j = g * 4 + jj;
                    const float* base = (j < 4) ? pw0 : (j < 8) ? pw1 : pw2;
                    const float* wp = base + (j & 3) * 2048 + ks * 32 + lg * 8;
                    wa[jj] = *(const float4*)(wp);
                    wc[jj] = *(const float4*)(wp + 4);
                }
                #pragma unroll
                for (int jj = 0; jj < 4; ++jj)
                    acc[g * 4 + jj] = __builtin_amdgcn_mfma_f32_16x16x32_bf16(
                        pack8(wa[jj], wc[jj]), xb[ks], acc[g * 4 + jj], 0, 0, 0);
            }
        }
    }

    // q -> wave scratch [t_loc][h]; k -> K[s][h]; v -> VT[h][s]
    #pragma unroll
    for (int j = 0; j < 4; ++j) {
        bf16x4 pk;
        pk[0] = (bf16_t)acc[j][0]; pk[1] = (bf16_t)acc[j][1];
        pk[2] = (bf16_t)acc[j][2]; pk[3] = (bf16_t)acc[j][3];
        *reinterpret_cast<bf16x4*>(qscr + swz(l15 * 128 + (j * 16 + lg * 4) * 2, l15)) = pk;
    }
    #pragma unroll
    for (int j = 4; j < 8; ++j) {
        bf16x4 pk;
        pk[0] = (bf16_t)acc[j][0]; pk[1] = (bf16_t)acc[j][1];
        pk[2] = (bf16_t)acc[j][2]; pk[3] = (bf16_t)acc[j][3];
        *reinterpret_cast<bf16x4*>(smem + swz(K_OFF + t * 128 + ((j - 4) * 16 + lg * 4) * 2, t)) = pk;
    }
    #pragma unroll
    for (int j = 8; j < 12; ++j)
        #pragma unroll
        for (int r = 0; r < 4; ++r) {
            int h = (j - 8) * 16 + lg * 4 + r;
            *reinterpret_cast<bf16_t*>(smem + swz(VT_OFF + h * 128 + t * 2, h)) = (bf16_t)acc[j][r];
        }
    __syncthreads();

    // ------------- S^T = K . q^T : lane = col t, regs = s ------------------
    f32x4 sacc[4];
    #pragma unroll
    for (int st = 0; st < 4; ++st) sacc[st] = (f32x4){0.f, 0.f, 0.f, 0.f};
    #pragma unroll
    for (int ks = 0; ks < 2; ++ks) {
        int h0 = ks * 32 + lg * 8;
        bf16x8 qf = *reinterpret_cast<const bf16x8*>(qscr + swz(l15 * 128 + h0 * 2, l15));
        #pragma unroll
        for (int st = 0; st < 4; ++st) {
            int s = st * 16 + l15;
            bf16x8 kf = *reinterpret_cast<const bf16x8*>(smem + swz(K_OFF + s * 128 + h0 * 2, s));
            sacc[st] = __builtin_amdgcn_mfma_f32_16x16x32_bf16(kf, qf, sacc[st], 0, 0, 0);
        }
    }

    // ------------- softmax: lane owns full row t (16 regs) -----------------
    float p[4][4];
    float m = -1e30f;
    #pragma unroll
    for (int st = 0; st < 4; ++st)
        #pragma unroll
        for (int r = 0; r < 4; ++r) {
            int s = st * 16 + lg * 4 + r;
            float v = sacc[st][r] * 0.125f;
            v = (s <= t) ? v : -1e30f;     // causal
            p[st][r] = v;
            m = fmaxf(m, v);
        }
    m = fmaxf(m, __shfl_xor(m, 16));
    m = fmaxf(m, __shfl_xor(m, 32));
    float sum = 0.f;
    #pragma unroll
    for (int st = 0; st < 4; ++st)
        #pragma unroll
        for (int r = 0; r < 4; ++r) {
            float e = __expf(p[st][r] - m);
            p[st][r] = e;
            sum += e;
        }
    sum += __shfl_xor(sum, 16);
    sum += __shfl_xor(sum, 32);
    float inv = 1.0f / sum;
    #pragma unroll
    for (int st = 0; st < 4; ++st) {
        bf16x4 pk;
        pk[0] = (bf16_t)(p[st][0] * inv); pk[1] = (bf16_t)(p[st][1] * inv);
        pk[2] = (bf16_t)(p[st][2] * inv); pk[3] = (bf16_t)(p[st][3] * inv);
        *reinterpret_cast<bf16x4*>(qscr + swz(l15 * 128 + (st * 16 + lg * 4) * 2, l15)) = pk;
    }
    // wave-private scratch: same-wave write->read, in-order, no barrier

    // ------------- out^T = V^T . P^T (swapped): lane = col t ---------------
    f32x4 oacc[4];
    #pragma unroll
    for (int ht = 0; ht < 4; ++ht) oacc[ht] = (f32x4){0.f, 0.f, 0.f, 0.f};
    #pragma unroll
    for (int ks = 0; ks < 2; ++ks) {
        int s0 = ks * 32 + lg * 8;
        bf16x8 pf = *reinterpret_cast<const bf16x8*>(qscr + swz(l15 * 128 + s0 * 2, l15));
        #pragma unroll
        for (int ht = 0; ht < 4; ++ht) {
            int h = ht * 16 + l15;
            bf16x8 vf = *reinterpret_cast<const bf16x8*>(smem + swz(VT_OFF + h * 128 + s0 * 2, h));
            oacc[ht] = __builtin_amdgcn_mfma_f32_16x16x32_bf16(vf, pf, oacc[ht], 0, 0, 0);
        }
    }

    float* ob = out + (size_t)b * 4096 + t * 64 + lg * 4;
    #pragma unroll
    for (int ht = 0; ht < 4; ++ht)
        *reinterpret_cast<float4*>(ob + ht * 16) =
            (float4){oacc[ht][0], oacc[ht][1], oacc[ht][2], oacc[ht][3]};
}

extern "C" void kernel_launch(void* const* d_in, const int* in_sizes, int n_in,
                              void* d_out, int out_size, void* d_ws, size_t ws_size,
                              hipStream_t stream) {
    const float* x  = (const float*)d_in[0];
    const float* Wq = (const float*)d_in[1];
    const float* Wk = (const float*)d_in[2];
    const float* Wv = (const float*)d_in[3];
    float* out = (float*)d_out;
    int B = in_sizes[0] / (64 * 128);   // 4096
    if (ws_size >= 192 * 128 * sizeof(bf16_t) && d_ws != nullptr) {
        bf16_t* w2 = (bf16_t*)d_ws;
        wcvt_kernel<<<24, 256, 0, stream>>>(Wq, Wk, Wv, w2);
        head_attn_kernel<true><<<B, 256, 0, stream>>>(x, Wq, Wk, Wv, w2, out);
    } else {
        head_attn_kernel<false><<<B, 256, 0, stream>>>(x, Wq, Wk, Wv, nullptr, out);
    }
}

// Round 8
// 72.363 us; speedup vs baseline: 1.1275x; 1.1275x over previous
//
#include <hip/hip_runtime.h>
#include <hip/hip_bf16.h>

// Single-head causal attention, B=4096, T=64, C=128, H=64.
// One block (4 waves) per batch.
// R8: x staged via global_load_lds (async, zero-VGPR, 32KB in flight per
// block) to fix the outstanding-bytes limit (R1-R7 all pinned at 1.35 TB/s
// effective = latency * tiny in-flight bytes). QKV restructured: wave w owns
// h-tiles {3w..3w+2} for ALL t -> W data is 12x16B held in regs, loaded
// during staging. v-tiles use flipped mfma operand order for packed VT writes.

typedef __bf16 bf16_t;
typedef __bf16 bf16x8 __attribute__((ext_vector_type(8)));
typedef __bf16 bf16x4 __attribute__((ext_vector_type(4)));
typedef float  f32x4  __attribute__((ext_vector_type(4)));

#define XF_OFF  0        // x f32 64x128, linear rows (512B), content col-swizzled; 32KB
#define Q_OFF   32768    // Q [t][h] 64x64 bf16, swizzled, 8KB
#define K_OFF   40960    // K [s][h] 8KB
#define VT_OFF  49152    // VT [h][t] 8KB
#define LDS_BYTES 57344  // 56KB -> 2 blocks/CU

__device__ __forceinline__ int swz(int off, int row) { return off ^ ((row & 7) << 4); }

__device__ __forceinline__ bf16x8 pack8(float4 a, float4 b) {
    bf16x8 r;
    r[0] = (bf16_t)a.x; r[1] = (bf16_t)a.y; r[2] = (bf16_t)a.z; r[3] = (bf16_t)a.w;
    r[4] = (bf16_t)b.x; r[5] = (bf16_t)b.y; r[6] = (bf16_t)b.z; r[7] = (bf16_t)b.w;
    return r;
}

__global__ __launch_bounds__(256) __attribute__((amdgpu_waves_per_eu(2, 2)))
void head_attn_kernel(const float* __restrict__ x,
                      const float* __restrict__ Wq,
                      const float* __restrict__ Wk,
                      const float* __restrict__ Wv,
                      float* __restrict__ out)
{
    __shared__ __align__(16) char smem[LDS_BYTES];
    const int b    = blockIdx.x;
    const int tid  = threadIdx.x;
    const int w    = tid >> 6;
    const int lane = tid & 63;
    const int l15  = lane & 15;
    const int lg   = lane >> 4;
    const int t    = w * 16 + l15;      // lane's query/time row in attention phase

    // ---- async stage x[b] (32 KB) -> LDS; linear dest, source pre-swizzled
    // so that reads at byte ((t*512 + c*4) ^ ((t&7)<<4)) return x[t][c].
    {
        const char* xg = (const char*)(x + (size_t)b * 8192);
        #pragma unroll
        for (int i = 0; i < 8; ++i) {
            int o   = (w * 8 + i) * 1024 + lane * 16;   // linear LDS byte slot
            int tr  = o >> 9;                           // row
            int c16 = (o >> 4) & 31;                    // 16B chunk in row
            int src = tr * 512 + ((c16 ^ (tr & 7)) << 4);
            __builtin_amdgcn_global_load_lds(
                (const __attribute__((address_space(1))) unsigned int*)(xg + src),
                (__attribute__((address_space(3))) unsigned int*)(smem + XF_OFF + (w * 8 + i) * 1024),
                16, 0, 0);
        }
    }

    // ---- W fragments for this wave's 3 h-tiles (overlaps staging) --------
    bf16x8 wf[3][4];
    #pragma unroll
    for (int j = 0; j < 3; ++j) {
        int hg = (3 * w + j) * 16 + l15;
        const float* wr = (hg < 64)  ? Wq + hg * 128
                        : (hg < 128) ? Wk + (hg - 64) * 128
                                     : Wv + (hg - 128) * 128;
        #pragma unroll
        for (int ks = 0; ks < 4; ++ks) {
            float4 a = *(const float4*)(wr + ks * 32 + lg * 8);
            float4 c = *(const float4*)(wr + ks * 32 + lg * 8 + 4);
            wf[j][ks] = pack8(a, c);
        }
    }

    asm volatile("s_waitcnt vmcnt(0)" ::: "memory");   // x staged
    __syncthreads();

    // ---- read all 16 x fragments (batched ds_reads), cvt to bf16 ---------
    bf16x8 xff[4][4];                                  // [ks][tt]
    #pragma unroll
    for (int ks = 0; ks < 4; ++ks)
        #pragma unroll
        for (int tt = 0; tt < 4; ++tt) {
            int tr = tt * 16 + l15;
            int cb = (ks * 32 + lg * 8) * 4;
            float4 xa = *(const float4*)(smem + XF_OFF + ((tr * 512 + cb) ^ ((tr & 7) << 4)));
            float4 xc = *(const float4*)(smem + XF_OFF + ((tr * 512 + cb + 16) ^ ((tr & 7) << 4)));
            xff[ks][tt] = pack8(xa, xc);
        }

    // ---- QKV: acc[j][tt], wave-uniform branch on tile type ---------------
    f32x4 acc[3][4];
    #pragma unroll
    for (int j = 0; j < 3; ++j)
        #pragma unroll
        for (int tt = 0; tt < 4; ++tt) acc[j][tt] = (f32x4){0.f, 0.f, 0.f, 0.f};

    #pragma unroll
    for (int j = 0; j < 3; ++j) {
        if (3 * w + j < 8) {       // q/k tile: D[h][t] (lane=t, regs=h)
            #pragma unroll
            for (int ks = 0; ks < 4; ++ks)
                #pragma unroll
                for (int tt = 0; tt < 4; ++tt)
                    acc[j][tt] = __builtin_amdgcn_mfma_f32_16x16x32_bf16(
                        wf[j][ks], xff[ks][tt], acc[j][tt], 0, 0, 0);
        } else {                   // v tile: D[t][h] (lane=h, regs=t) -> packed VT
            #pragma unroll
            for (int ks = 0; ks < 4; ++ks)
                #pragma unroll
                for (int tt = 0; tt < 4; ++tt)
                    acc[j][tt] = __builtin_amdgcn_mfma_f32_16x16x32_bf16(
                        xff[ks][tt], wf[j][ks], acc[j][tt], 0, 0, 0);
        }
    }

    // ---- write q/k (scatter b16) and v (packed b64, transposed) ----------
    #pragma unroll
    for (int j = 0; j < 3; ++j) {
        int tile = 3 * w + j;
        if (tile < 8) {
            int base = (tile < 4) ? Q_OFF : K_OFF;
            int h0 = (tile & 3) * 16 + lg * 4;
            #pragma unroll
            for (int tt = 0; tt < 4; ++tt) {
                int tr = tt * 16 + l15;
                #pragma unroll
                for (int r = 0; r < 4; ++r)
                    *(bf16_t*)(smem + base + swz(tr * 128 + (h0 + r) * 2, tr)) =
                        (bf16_t)acc[j][tt][r];
            }
        } else {
            int hv = (tile - 8) * 16 + l15;
            #pragma unroll
            for (int tt = 0; tt < 4; ++tt) {
                bf16x4 pk;
                pk[0] = (bf16_t)acc[j][tt][0]; pk[1] = (bf16_t)acc[j][tt][1];
                pk[2] = (bf16_t)acc[j][tt][2]; pk[3] = (bf16_t)acc[j][tt][3];
                *(bf16x4*)(smem + VT_OFF + swz(hv * 128 + (tt * 16 + lg * 4) * 2, hv)) = pk;
            }
        }
    }
    __syncthreads();

    // ---- S^T = K . q^T : lane = col t (own row), regs = s ----------------
    char* pscr = smem + XF_OFF + w * 2048;     // P scratch reuses XF region
    f32x4 sacc[4];
    #pragma unroll
    for (int st = 0; st < 4; ++st) sacc[st] = (f32x4){0.f, 0.f, 0.f, 0.f};
    #pragma unroll
    for (int ks = 0; ks < 2; ++ks) {
        int h0 = ks * 32 + lg * 8;
        bf16x8 qf = *(const bf16x8*)(smem + Q_OFF + swz(t * 128 + h0 * 2, t));
        #pragma unroll
        for (int st = 0; st < 4; ++st) {
            int s = st * 16 + l15;
            bf16x8 kf = *(const bf16x8*)(smem + K_OFF + swz(s * 128 + h0 * 2, s));
            sacc[st] = __builtin_amdgcn_mfma_f32_16x16x32_bf16(kf, qf, sacc[st], 0, 0, 0);
        }
    }

    // ---- softmax: each lane owns full row t ------------------------------
    float p[4][4];
    float m = -1e30f;
    #pragma unroll
    for (int st = 0; st < 4; ++st)
        #pragma unroll
        for (int r = 0; r < 4; ++r) {
            int s = st * 16 + lg * 4 + r;
            float v = sacc[st][r] * 0.125f;
            v = (s <= t) ? v : -1e30f;     // causal
            p[st][r] = v;
            m = fmaxf(m, v);
        }
    m = fmaxf(m, __shfl_xor(m, 16));
    m = fmaxf(m, __shfl_xor(m, 32));
    float sum = 0.f;
    #pragma unroll
    for (int st = 0; st < 4; ++st)
        #pragma unroll
        for (int r = 0; r < 4; ++r) {
            float e = __expf(p[st][r] - m);
            p[st][r] = e;
            sum += e;
        }
    sum += __shfl_xor(sum, 16);
    sum += __shfl_xor(sum, 32);
    float inv = 1.0f / sum;
    #pragma unroll
    for (int st = 0; st < 4; ++st) {
        bf16x4 pk;
        pk[0] = (bf16_t)(p[st][0] * inv); pk[1] = (bf16_t)(p[st][1] * inv);
        pk[2] = (bf16_t)(p[st][2] * inv); pk[3] = (bf16_t)(p[st][3] * inv);
        *(bf16x4*)(pscr + swz(l15 * 128 + (st * 16 + lg * 4) * 2, l15)) = pk;
    }
    // wave-private scratch: same-wave write->read, in-order, no barrier

    // ---- out^T = V^T . P^T (swapped): lane = col t -----------------------
    f32x4 oacc[4];
    #pragma unroll
    for (int ht = 0; ht < 4; ++ht) oacc[ht] = (f32x4){0.f, 0.f, 0.f, 0.f};
    #pragma unroll
    for (int ks = 0; ks < 2; ++ks) {
        int s0 = ks * 32 + lg * 8;
        bf16x8 pf = *(const bf16x8*)(pscr + swz(l15 * 128 + s0 * 2, l15));
        #pragma unroll
        for (int ht = 0; ht < 4; ++ht) {
            int h = ht * 16 + l15;
            bf16x8 vf = *(const bf16x8*)(smem + VT_OFF + swz(h * 128 + s0 * 2, h));
            oacc[ht] = __builtin_amdgcn_mfma_f32_16x16x32_bf16(vf, pf, oacc[ht], 0, 0, 0);
        }
    }

    float* ob = out + (size_t)b * 4096 + t * 64 + lg * 4;
    #pragma unroll
    for (int ht = 0; ht < 4; ++ht)
        *(float4*)(ob + ht * 16) =
            (float4){oacc[ht][0], oacc[ht][1], oacc[ht][2], oacc[ht][3]};
}

extern "C" void kernel_launch(void* const* d_in, const int* in_sizes, int n_in,
                              void* d_out, int out_size, void* d_ws, size_t ws_size,
                              hipStream_t stream) {
    const float* x  = (const float*)d_in[0];
    const float* Wq = (const float*)d_in[1];
    const float* Wk = (const float*)d_in[2];
    const float* Wv = (const float*)d_in[3];
    float* out = (float*)d_out;
    int B = in_sizes[0] / (64 * 128);   // 4096
    head_attn_kernel<<<B, 256, 0, stream>>>(x, Wq, Wk, Wv, out);
}

// Round 9
// 44.371 us; speedup vs baseline: 1.8387x; 1.6309x over previous
//
#include <hip/hip_runtime.h>
#include <hip/hip_bf16.h>

// Single-head causal attention, B=4096, T=64, C=128, H=64.
// Grid 512 x 256thr (2 blocks/CU), NB=8 batches per block, software-pipelined:
// W staged once into LDS as pre-permuted bf16 MFMA fragments (conflict-free
// contiguous ds_read_b128); x rows live in registers with cross-batch
// prefetch so HBM reads flow continuously (R1-R8 all pinned at ~1.4 TB/s
// because each block's single stage burst was followed by a long no-traffic
// compute chain). Wave w owns query rows [16w,16w+16); v-tiles use flipped
// mfma operand order (validated R8) for packed VT writes; attention phase
// is the validated R6 code.

typedef __bf16 bf16_t;
typedef __bf16 bf16x8 __attribute__((ext_vector_type(8)));
typedef __bf16 bf16x4 __attribute__((ext_vector_type(4)));
typedef float  f32x4  __attribute__((ext_vector_type(4)));

#define WL_OFF  0        // W bf16 fragments: byte ((ks*12+j)*64+lane)*16, 48 KB
#define K_OFF   49152    // K [s][h] 64x64 bf16, swizzled, 8 KB
#define VT_OFF  57344    // VT [h][t] 64x64 bf16, swizzled, 8 KB
#define QS_OFF  65536    // per-wave scratch (q then P): w*2048, 16x64 bf16, 8 KB
#define LDS_BYTES 73728  // 72 KB -> 2 blocks/CU

__device__ __forceinline__ int swz(int off, int row) { return off ^ ((row & 7) << 4); }

__device__ __forceinline__ bf16x8 pack8(float4 a, float4 b) {
    bf16x8 r;
    r[0] = (bf16_t)a.x; r[1] = (bf16_t)a.y; r[2] = (bf16_t)a.z; r[3] = (bf16_t)a.w;
    r[4] = (bf16_t)b.x; r[5] = (bf16_t)b.y; r[6] = (bf16_t)b.z; r[7] = (bf16_t)b.w;
    return r;
}

__global__ __launch_bounds__(256) __attribute__((amdgpu_waves_per_eu(2, 2)))
void head_attn_kernel(const float* __restrict__ x,
                      const float* __restrict__ Wq,
                      const float* __restrict__ Wk,
                      const float* __restrict__ Wv,
                      float* __restrict__ out,
                      int NB)
{
    __shared__ __align__(16) char smem[LDS_BYTES];
    const int tid  = threadIdx.x;
    const int w    = tid >> 6;
    const int lane = tid & 63;
    const int l15  = lane & 15;
    const int lg   = lane >> 4;
    const int t    = w * 16 + l15;          // lane's owned query/time row
    char* qscr = smem + QS_OFF + w * 2048;

    // ---- stage W -> LDS once, pre-permuted into per-lane 16B fragments ----
    // chunk c = (ks*12 + j)*64 + ln holds W[h = j*16 + (ln&15)][ks*32+(ln>>4)*8 ..+8)
    #pragma unroll
    for (int i = 0; i < 12; ++i) {
        int c   = i * 256 + tid;
        int ks  = i / 3;                      // == c/768 (compile-time per i)
        int rem = c - ks * 768;
        int j   = rem >> 6;
        int ln  = rem & 63;
        int h   = j * 16 + (ln & 15);
        int c0  = ks * 32 + (ln >> 4) * 8;
        const float* wr = (h < 64)  ? Wq + h * 128
                        : (h < 128) ? Wk + (h - 64) * 128
                                    : Wv + (h - 128) * 128;
        float4 a  = *(const float4*)(wr + c0);
        float4 bb = *(const float4*)(wr + c0 + 4);
        *(bf16x8*)(smem + WL_OFF + c * 16) = pack8(a, bb);
    }

    // ---- prefetch first batch's x row (8 independent float4, 32 VGPRs) ----
    const size_t b0 = (size_t)blockIdx.x * NB;
    const float* xrow = x + b0 * 8192 + t * 128 + lg * 8;
    float4 xr[8];
    #pragma unroll
    for (int k = 0; k < 8; ++k)
        xr[k] = *(const float4*)(xrow + (k >> 1) * 32 + (k & 1) * 4);

    __syncthreads();   // W staged (also drains first prefetch; harmless)

    for (int i = 0; i < NB; ++i) {
        // current batch's x -> bf16 MFMA fragments
        bf16x8 xb[4];
        #pragma unroll
        for (int ks = 0; ks < 4; ++ks) xb[ks] = pack8(xr[2 * ks], xr[2 * ks + 1]);

        // issue next batch's x loads (overlap QKV + attention below)
        if (i + 1 < NB) {
            const float* xn = xrow + (size_t)(i + 1) * 8192;
            #pragma unroll
            for (int k = 0; k < 8; ++k)
                xr[k] = *(const float4*)(xn + (k >> 1) * 32 + (k & 1) * 4);
        }

        // ------------- QKV: all 12 h-tiles for this wave's t-tile ----------
        // j 0..7 (q,k): acc = mfma(wf, xb) -> D[h][t], lane = t, regs = h
        // j 8..11 (v):  acc = mfma(xb, wf) -> D[t][h], lane = h, regs = t
        f32x4 acc[12];
        #pragma unroll
        for (int j = 0; j < 12; ++j) acc[j] = (f32x4){0.f, 0.f, 0.f, 0.f};

        #pragma unroll
        for (int ks = 0; ks < 4; ++ks) {
            bf16x8 wf[12];                    // 12 contiguous conflict-free b128
            #pragma unroll
            for (int j = 0; j < 12; ++j)
                wf[j] = *(const bf16x8*)(smem + WL_OFF + ((ks * 12 + j) * 64 + lane) * 16);
            #pragma unroll
            for (int j = 0; j < 12; ++j) {
                if (j < 8)
                    acc[j] = __builtin_amdgcn_mfma_f32_16x16x32_bf16(wf[j], xb[ks], acc[j], 0, 0, 0);
                else
                    acc[j] = __builtin_amdgcn_mfma_f32_16x16x32_bf16(xb[ks], wf[j], acc[j], 0, 0, 0);
            }
        }

        // q -> wave scratch [t_loc][h]; k -> K[s][h]; v -> VT[h][t] (all b64)
        #pragma unroll
        for (int j = 0; j < 4; ++j) {
            bf16x4 pk;
            pk[0] = (bf16_t)acc[j][0]; pk[1] = (bf16_t)acc[j][1];
            pk[2] = (bf16_t)acc[j][2]; pk[3] = (bf16_t)acc[j][3];
            *(bf16x4*)(qscr + swz(l15 * 128 + (j * 16 + lg * 4) * 2, l15)) = pk;
        }
        #pragma unroll
        for (int j = 4; j < 8; ++j) {
            bf16x4 pk;
            pk[0] = (bf16_t)acc[j][0]; pk[1] = (bf16_t)acc[j][1];
            pk[2] = (bf16_t)acc[j][2]; pk[3] = (bf16_t)acc[j][3];
            *(bf16x4*)(smem + K_OFF + swz(t * 128 + ((j - 4) * 16 + lg * 4) * 2, t)) = pk;
        }
        #pragma unroll
        for (int j = 8; j < 12; ++j) {
            int hv = (j - 8) * 16 + l15;      // acc[j][r] = V[t = w*16+lg*4+r][hv]
            bf16x4 pk;
            pk[0] = (bf16_t)acc[j][0]; pk[1] = (bf16_t)acc[j][1];
            pk[2] = (bf16_t)acc[j][2]; pk[3] = (bf16_t)acc[j][3];
            *(bf16x4*)(smem + VT_OFF + swz(hv * 128 + (w * 16 + lg * 4) * 2, hv)) = pk;
        }
        __syncthreads();

        // ------------- S^T = K . q^T : lane = col t (own row), regs = s ----
        f32x4 sacc[4];
        #pragma unroll
        for (int st = 0; st < 4; ++st) sacc[st] = (f32x4){0.f, 0.f, 0.f, 0.f};
        #pragma unroll
        for (int ks = 0; ks < 2; ++ks) {
            int h0 = ks * 32 + lg * 8;
            bf16x8 qf = *(const bf16x8*)(qscr + swz(l15 * 128 + h0 * 2, l15));
            #pragma unroll
            for (int st = 0; st < 4; ++st) {
                int s = st * 16 + l15;
                bf16x8 kf = *(const bf16x8*)(smem + K_OFF + swz(s * 128 + h0 * 2, s));
                sacc[st] = __builtin_amdgcn_mfma_f32_16x16x32_bf16(kf, qf, sacc[st], 0, 0, 0);
            }
        }

        // ------------- softmax: each lane owns full row t ------------------
        float p[4][4];
        float m = -1e30f;
        #pragma unroll
        for (int st = 0; st < 4; ++st)
            #pragma unroll
            for (int r = 0; r < 4; ++r) {
                int s = st * 16 + lg * 4 + r;
                float v = sacc[st][r] * 0.125f;
                v = (s <= t) ? v : -1e30f;     // causal
                p[st][r] = v;
                m = fmaxf(m, v);
            }
        m = fmaxf(m, __shfl_xor(m, 16));
        m = fmaxf(m, __shfl_xor(m, 32));
        float sum = 0.f;
        #pragma unroll
        for (int st = 0; st < 4; ++st)
            #pragma unroll
            for (int r = 0; r < 4; ++r) {
                float e = __expf(p[st][r] - m);
                p[st][r] = e;
                sum += e;
            }
        sum += __shfl_xor(sum, 16);
        sum += __shfl_xor(sum, 32);
        float inv = 1.0f / sum;
        #pragma unroll
        for (int st = 0; st < 4; ++st) {
            bf16x4 pk;
            pk[0] = (bf16_t)(p[st][0] * inv); pk[1] = (bf16_t)(p[st][1] * inv);
            pk[2] = (bf16_t)(p[st][2] * inv); pk[3] = (bf16_t)(p[st][3] * inv);
            *(bf16x4*)(qscr + swz(l15 * 128 + (st * 16 + lg * 4) * 2, l15)) = pk;
        }
        // wave-private scratch: same-wave write->read, in-order, no barrier

        // ------------- out^T = V^T . P^T (swapped): lane = col t -----------
        f32x4 oacc[4];
        #pragma unroll
        for (int ht = 0; ht < 4; ++ht) oacc[ht] = (f32x4){0.f, 0.f, 0.f, 0.f};
        #pragma unroll
        for (int ks = 0; ks < 2; ++ks) {
            int s0 = ks * 32 + lg * 8;
            bf16x8 pf = *(const bf16x8*)(qscr + swz(l15 * 128 + s0 * 2, l15));
            #pragma unroll
            for (int ht = 0; ht < 4; ++ht) {
                int h = ht * 16 + l15;
                bf16x8 vf = *(const bf16x8*)(smem + VT_OFF + swz(h * 128 + s0 * 2, h));
                oacc[ht] = __builtin_amdgcn_mfma_f32_16x16x32_bf16(vf, pf, oacc[ht], 0, 0, 0);
            }
        }

        float* ob = out + (b0 + i) * 4096 + t * 64 + lg * 4;
        #pragma unroll
        for (int ht = 0; ht < 4; ++ht)
            *(float4*)(ob + ht * 16) =
                (float4){oacc[ht][0], oacc[ht][1], oacc[ht][2], oacc[ht][3]};

        __syncthreads();   // protect K/VT/QS before next iteration's writes
    }
}

extern "C" void kernel_launch(void* const* d_in, const int* in_sizes, int n_in,
                              void* d_out, int out_size, void* d_ws, size_t ws_size,
                              hipStream_t stream) {
    const float* x  = (const float*)d_in[0];
    const float* Wq = (const float*)d_in[1];
    const float* Wk = (const float*)d_in[2];
    const float* Wv = (const float*)d_in[3];
    float* out = (float*)d_out;
    int B = in_sizes[0] / (64 * 128);   // 4096
    int grid = 512;                     // 2 blocks/CU
    int NB = B / grid;                  // 8 batches per block
    head_attn_kernel<<<grid, 256, 0, stream>>>(x, Wq, Wk, Wv, out, NB);
}